// Round 2
// baseline (293.537 us; speedup 1.0000x reference)
//
#include <hip/hip_runtime.h>
#include <hip/hip_bf16.h>

// Linear1d: out[B,256] = (x[B,512] @ W[256,512]^T) / 8 + 0.1*bias
// R2: latency-bound fix — BM 64->32 (2048 blocks, 2x TLP), explicit
// register software-pipeline (prefetch chunk k+1 before MFMA of chunk k),
// nontemporal output stores. LDS-free bf16 MFMA, scale folded into W.

typedef __bf16 bf16;
typedef __attribute__((ext_vector_type(8))) __bf16 bf16x8;
typedef __attribute__((ext_vector_type(4))) __bf16 bf16x4;
typedef __attribute__((ext_vector_type(4))) float f32x4;

#define BATCH_ 65536
#define KDIM   512
#define NDIM   256
#define BM     32
#define NCHUNK 16   // 512 / 32

__global__ __launch_bounds__(256) void wcvt_kernel(const float* __restrict__ w,
                                                   bf16* __restrict__ wb) {
    int i = (blockIdx.x * 256 + threadIdx.x) * 4;
    f32x4 v = *(const f32x4*)(w + i);
    bf16x4 o;
    o[0] = (bf16)(v.x * 0.125f);
    o[1] = (bf16)(v.y * 0.125f);
    o[2] = (bf16)(v.z * 0.125f);
    o[3] = (bf16)(v.w * 0.125f);
    *(bf16x4*)(wb + i) = o;
}

__device__ __forceinline__ bf16x8 cvt_a(f32x4 lo, f32x4 hi) {
    bf16x8 a;
    a[0] = (bf16)lo.x; a[1] = (bf16)lo.y; a[2] = (bf16)lo.z; a[3] = (bf16)lo.w;
    a[4] = (bf16)hi.x; a[5] = (bf16)hi.y; a[6] = (bf16)hi.z; a[7] = (bf16)hi.w;
    return a;
}

__global__ __launch_bounds__(256, 4) void gemm_kernel(const float* __restrict__ x,
                                                      const bf16* __restrict__ wb,
                                                      const float* __restrict__ bias,
                                                      float* __restrict__ out) {
    const int lane = threadIdx.x & 63;
    const int wv   = threadIdx.x >> 6;   // wave -> N quarter
    const int q    = lane >> 4;          // k-quad 0..3
    const int l16  = lane & 15;
    const long m0  = (long)blockIdx.x * BM;
    const int  n0  = wv * 64;

    // A layout (16x16x32): A[m=lane&15][k=q*8+j]; B: W[n=lane&15][k=q*8+j]
    const float* xp[2];
    const bf16*  wp[4];
#pragma unroll
    for (int t = 0; t < 2; ++t)
        xp[t] = x + (m0 + t * 16 + l16) * KDIM + q * 8;
#pragma unroll
    for (int t = 0; t < 4; ++t)
        wp[t] = wb + (long)(n0 + t * 16 + l16) * KDIM + q * 8;

    f32x4 acc[2][4];
#pragma unroll
    for (int i = 0; i < 2; ++i)
#pragma unroll
        for (int j = 0; j < 4; ++j)
            acc[i][j] = (f32x4)0.0f;

    // Software pipeline over 16 k-chunks of 32: raw loads held in f32/bf16
    // regs one chunk ahead; fully unrolled so the compiler SSA-renames.
    f32x4 alo[NCHUNK][2], ahi[NCHUNK][2];
    bf16x8 bfr[NCHUNK][4];

    // prefetch chunk 0
#pragma unroll
    for (int mt = 0; mt < 2; ++mt) {
        alo[0][mt] = *(const f32x4*)(xp[mt]);
        ahi[0][mt] = *(const f32x4*)(xp[mt] + 4);
    }
#pragma unroll
    for (int nt = 0; nt < 4; ++nt)
        bfr[0][nt] = *(const bf16x8*)(wp[nt]);

#pragma unroll
    for (int kc = 0; kc < NCHUNK; ++kc) {
        if (kc + 1 < NCHUNK) {   // prefetch next chunk (compile-time branch)
#pragma unroll
            for (int mt = 0; mt < 2; ++mt) {
                alo[kc + 1][mt] = *(const f32x4*)(xp[mt] + (kc + 1) * 32);
                ahi[kc + 1][mt] = *(const f32x4*)(xp[mt] + (kc + 1) * 32 + 4);
            }
#pragma unroll
            for (int nt = 0; nt < 4; ++nt)
                bfr[kc + 1][nt] = *(const bf16x8*)(wp[nt] + (kc + 1) * 32);
        }
        bf16x8 a[2];
#pragma unroll
        for (int mt = 0; mt < 2; ++mt)
            a[mt] = cvt_a(alo[kc][mt], ahi[kc][mt]);
#pragma unroll
        for (int mt = 0; mt < 2; ++mt)
#pragma unroll
            for (int nt = 0; nt < 4; ++nt)
                acc[mt][nt] = __builtin_amdgcn_mfma_f32_16x16x32_bf16(
                    a[mt], bfr[kc][nt], acc[mt][nt], 0, 0, 0);
    }

    // Epilogue. C/D layout: col = lane&15, row = q*4 + reg.
    float bv[4];
#pragma unroll
    for (int nt = 0; nt < 4; ++nt)
        bv[nt] = 0.1f * bias[n0 + nt * 16 + l16];

#pragma unroll
    for (int mt = 0; mt < 2; ++mt)
#pragma unroll
        for (int nt = 0; nt < 4; ++nt)
#pragma unroll
            for (int r = 0; r < 4; ++r) {
                long row = m0 + mt * 16 + q * 4 + r;
                __builtin_nontemporal_store(acc[mt][nt][r] + bv[nt],
                                            &out[row * NDIM + n0 + nt * 16 + l16]);
            }
}

extern "C" void kernel_launch(void* const* d_in, const int* in_sizes, int n_in,
                              void* d_out, int out_size, void* d_ws, size_t ws_size,
                              hipStream_t stream) {
    const float* x    = (const float*)d_in[0];
    const float* w    = (const float*)d_in[1];
    const float* bias = (const float*)d_in[2];
    float* out = (float*)d_out;
    bf16* wb   = (bf16*)d_ws;   // 256*512*2 = 256 KB scratch

    wcvt_kernel<<<(NDIM * KDIM) / (256 * 4), 256, 0, stream>>>(w, wb);
    gemm_kernel<<<BATCH_ / BM, 256, 0, stream>>>(x, wb, bias, out);
}

// Round 3
// 233.879 us; speedup vs baseline: 1.2551x; 1.2551x over previous
//
#include <hip/hip_runtime.h>
#include <hip/hip_bf16.h>

// Linear1d: out[B,256] = (x[B,512] @ W[256,512]^T) / 8 + 0.1*bias
// R3: W stationary in VGPRs (64 regs/wave, zero steady-state W loads);
// x staged fp32->bf16 into double-buffered LDS (XOR-swizzled); pipeline
// [commit(t); barrier; issue(t+1); compute(t)] => barrier drain is free.

typedef __bf16 bf16;
typedef __attribute__((ext_vector_type(8))) __bf16 bf16x8;
typedef __attribute__((ext_vector_type(4))) __bf16 bf16x4;
typedef __attribute__((ext_vector_type(4))) float f32x4;

#define BATCH_ 65536
#define KDIM   512
#define NDIM   256
#define ROWS_PER_CHUNK   32
#define CHUNKS_PER_BLOCK 8
#define ROWS_PER_BLOCK   256   // 8 chunks * 32 rows
#define BN_BLOCK 128           // N per block (2 n-groups)
#define BN_WAVE  16            // N per wave (8 waves)

__global__ __launch_bounds__(256) void wcvt_kernel(const float* __restrict__ w,
                                                   bf16* __restrict__ wb) {
    int i = (blockIdx.x * 256 + threadIdx.x) * 4;
    f32x4 v = *(const f32x4*)(w + i);
    bf16x4 o;
    o[0] = (bf16)(v.x * 0.125f);
    o[1] = (bf16)(v.y * 0.125f);
    o[2] = (bf16)(v.z * 0.125f);
    o[3] = (bf16)(v.w * 0.125f);
    *(bf16x4*)(wb + i) = o;
}

__global__ __launch_bounds__(512, 2) void gemm_kernel(const float* __restrict__ x,
                                                      const bf16* __restrict__ wb,
                                                      const float* __restrict__ bias,
                                                      float* __restrict__ out) {
    // LDS: double-buffered bf16 x-chunk, 32 rows x 512 cols = 32 KB per buf.
    // Layout: row rr at byte rr*1024; 16B granule g stored at g ^ (rr & 7).
    __shared__ __align__(16) char lds[2][32 * 1024];

    const int tid  = threadIdx.x;
    const int lane = tid & 63;
    const int w    = tid >> 6;       // wave 0..7
    const int q    = lane >> 4;      // k-quad
    const int l16  = lane & 15;

    const int  ng = blockIdx.x & 1;
    const long mg = blockIdx.x >> 1;
    const long row_base = mg * ROWS_PER_BLOCK;
    const int  n0 = ng * BN_BLOCK + w * BN_WAVE;

    // --- W stationary: B-frag[kc] = W[n0+l16][kc*32 + q*8 .. +7] ---
    bf16x8 wf[16];
#pragma unroll
    for (int kc = 0; kc < 16; ++kc)
        wf[kc] = *(const bf16x8*)(wb + (long)(n0 + l16) * KDIM + kc * 32 + q * 8);

    const float bv = 0.1f * bias[n0 + l16];

    // Staging: wave stages rows rr = w*4 + j (j=0..3), two 1KB halves each.
    // Global: perfectly coalesced 16B/lane.
    const float* xw = x + (row_base + (long)w * 4) * KDIM + lane * 4;

    f32x4 ld[8];
#pragma unroll
    for (int j = 0; j < 4; ++j)
#pragma unroll
        for (int h = 0; h < 2; ++h)
            ld[j * 2 + h] = *(const f32x4*)(xw + (long)j * KDIM + h * 256);

    for (int t = 0; t < CHUNKS_PER_BLOCK; ++t) {
        char* buf = lds[t & 1];

        // ---- commit(t): wait loads, cvt fp32->bf16, ds_write swizzled ----
#pragma unroll
        for (int j = 0; j < 4; ++j) {
            const int rr = w * 4 + j;
#pragma unroll
            for (int h = 0; h < 2; ++h) {
                f32x4 v = ld[j * 2 + h];
                bf16x4 o;
                o[0] = (bf16)v.x; o[1] = (bf16)v.y;
                o[2] = (bf16)v.z; o[3] = (bf16)v.w;
                const int g  = h * 32 + (lane >> 1);          // 16B granule
                const int gs = g ^ (rr & 7);
                *(bf16x4*)(buf + rr * 1024 + gs * 16 + (lane & 1) * 8) = o;
            }
        }

        __syncthreads();   // nothing in flight here -> drain is free

        // ---- issue(t+1): fly under compute(t) ----
        if (t + 1 < CHUNKS_PER_BLOCK) {
#pragma unroll
            for (int j = 0; j < 4; ++j)
#pragma unroll
                for (int h = 0; h < 2; ++h)
                    ld[j * 2 + h] = *(const f32x4*)(xw + ((long)(t + 1) * 32 + j) * KDIM + h * 256);
        }

        // ---- compute(t): 16 k-chunks, 2 m-frags, MFMA vs stationary W ----
        f32x4 acc[2];
        acc[0] = (f32x4)0.0f;
        acc[1] = (f32x4)0.0f;
#pragma unroll
        for (int kc = 0; kc < 16; ++kc) {
#pragma unroll
            for (int mt = 0; mt < 2; ++mt) {
                const int rr = mt * 16 + l16;
                const int gs = (kc * 4 + q) ^ (rr & 7);
                bf16x8 a = *(const bf16x8*)(buf + rr * 1024 + gs * 16);
                acc[mt] = __builtin_amdgcn_mfma_f32_16x16x32_bf16(a, wf[kc], acc[mt], 0, 0, 0);
            }
        }

        // ---- epilogue(t): C/D layout row = q*4+r, col = l16 ----
        const long row0 = row_base + (long)t * ROWS_PER_CHUNK;
#pragma unroll
        for (int mt = 0; mt < 2; ++mt)
#pragma unroll
            for (int r = 0; r < 4; ++r)
                out[(row0 + mt * 16 + q * 4 + r) * NDIM + n0 + l16] = acc[mt][r] + bv;
    }
}

extern "C" void kernel_launch(void* const* d_in, const int* in_sizes, int n_in,
                              void* d_out, int out_size, void* d_ws, size_t ws_size,
                              hipStream_t stream) {
    const float* x    = (const float*)d_in[0];
    const float* w    = (const float*)d_in[1];
    const float* bias = (const float*)d_in[2];
    float* out = (float*)d_out;
    bf16* wb   = (bf16*)d_ws;   // 256*512*2 = 256 KB scratch

    wcvt_kernel<<<(NDIM * KDIM) / (256 * 4), 256, 0, stream>>>(w, wb);
    gemm_kernel<<<(BATCH_ / ROWS_PER_BLOCK) * (NDIM / BN_BLOCK), 512, 0, stream>>>(x, wb, bias, out);
}

// Round 4
// 230.939 us; speedup vs baseline: 1.2711x; 1.0127x over previous
//
#include <hip/hip_runtime.h>
#include <hip/hip_bf16.h>

// Linear1d: out[B,256] = (x[B,512] @ W[256,512]^T) / 8 + 0.1*bias
// R4: achieved-BW fix. x staged fp32 via global_load_lds (zero-VGPR DMA, deep
// vmcnt queue) into two statically-distinct LDS buffers (alias-analysis keeps
// the prefetch in flight across compute); W stationary 128 VGPR covering all
// N=256 per block (x loaded CU-side exactly once); stores drained one phase
// late. One __syncthreads per 16-row chunk.

typedef __bf16 bf16;
typedef __attribute__((ext_vector_type(8))) __bf16 bf16x8;
typedef __attribute__((ext_vector_type(4))) __bf16 bf16x4;
typedef __attribute__((ext_vector_type(4))) float f32x4;

#define BATCH_ 65536
#define KDIM   512
#define NDIM   256
#define CHUNK_ROWS 16
#define CHUNKS 16                  // per block
#define ROWS_PER_BLOCK (CHUNK_ROWS * CHUNKS)   // 256
#define CHUNK_BYTES (CHUNK_ROWS * KDIM * 4)    // 32 KB

__global__ __launch_bounds__(256) void wcvt_kernel(const float* __restrict__ w,
                                                   bf16* __restrict__ wb) {
    int i = (blockIdx.x * 256 + threadIdx.x) * 4;
    f32x4 v = *(const f32x4*)(w + i);
    bf16x4 o;
    o[0] = (bf16)(v.x * 0.125f);
    o[1] = (bf16)(v.y * 0.125f);
    o[2] = (bf16)(v.z * 0.125f);
    o[3] = (bf16)(v.w * 0.125f);
    *(bf16x4*)(wb + i) = o;
}

__device__ __forceinline__ void stage_chunk(const float* xc, float* buf, int tid) {
    // 32 KB chunk: 4 passes x (512 thr x 16 B). LDS dest is wave-uniform
    // base + lane*16 (linear deposit, matches global order exactly).
#pragma unroll
    for (int p = 0; p < 4; ++p) {
        const char* g = (const char*)xc + p * 8192 + tid * 16;
        char* l = (char*)buf + p * 8192 + (tid >> 6) * 1024;
        __builtin_amdgcn_global_load_lds(
            (const __attribute__((address_space(1))) void*)g,
            (__attribute__((address_space(3))) void*)l, 16, 0, 0);
    }
}

__device__ __forceinline__ bf16x8 cvt_a(f32x4 lo, f32x4 hi) {
    bf16x8 a;
    a[0] = (bf16)lo.x; a[1] = (bf16)lo.y; a[2] = (bf16)lo.z; a[3] = (bf16)lo.w;
    a[4] = (bf16)hi.x; a[5] = (bf16)hi.y; a[6] = (bf16)hi.z; a[7] = (bf16)hi.w;
    return a;
}

__device__ __forceinline__ void compute_chunk(const float* buf,
                                              const bf16x8 (&wf)[16][2],
                                              int l16, int q, f32x4 (&acc)[2]) {
    acc[0] = (f32x4)0.0f;
    acc[1] = (f32x4)0.0f;
    const float* rowp = buf + l16 * KDIM + q * 8;
#pragma unroll
    for (int kc = 0; kc < 16; ++kc) {
        f32x4 lo = *(const f32x4*)(rowp + kc * 32);
        f32x4 hi = *(const f32x4*)(rowp + kc * 32 + 4);
        bf16x8 a = cvt_a(lo, hi);
        acc[0] = __builtin_amdgcn_mfma_f32_16x16x32_bf16(a, wf[kc][0], acc[0], 0, 0, 0);
        acc[1] = __builtin_amdgcn_mfma_f32_16x16x32_bf16(a, wf[kc][1], acc[1], 0, 0, 0);
    }
}

__global__ __launch_bounds__(512, 2) void gemm_kernel(const float* __restrict__ x,
                                                      const bf16* __restrict__ wb,
                                                      const float* __restrict__ bias,
                                                      float* __restrict__ out) {
    __shared__ __align__(16) float bufA[CHUNK_ROWS * KDIM];  // 32 KB
    __shared__ __align__(16) float bufB[CHUNK_ROWS * KDIM];  // 32 KB

    const int tid  = threadIdx.x;
    const int lane = tid & 63;
    const int w    = tid >> 6;     // wave 0..7 -> 32 N-columns each
    const int q    = lane >> 4;
    const int l16  = lane & 15;
    const int n0   = w * 32;
    const long row_base = (long)blockIdx.x * ROWS_PER_BLOCK;

    // Stationary W: wf[kc][nt] = W[n0+nt*16+l16][kc*32+q*8 .. +7]  (128 VGPR)
    bf16x8 wf[16][2];
#pragma unroll
    for (int kc = 0; kc < 16; ++kc)
#pragma unroll
        for (int nt = 0; nt < 2; ++nt)
            wf[kc][nt] = *(const bf16x8*)(wb + (long)(n0 + nt * 16 + l16) * KDIM
                                             + kc * 32 + q * 8);
    float bv[2];
    bv[0] = 0.1f * bias[n0 + l16];
    bv[1] = 0.1f * bias[n0 + 16 + l16];

    const float* xblk = x + row_base * KDIM;

    // Prologue: chunk 0 -> bufA.
    stage_chunk(xblk, bufA, tid);
    __syncthreads();

    f32x4 acc[2];
#pragma unroll 1
    for (int t = 0; t < CHUNKS; t += 2) {
        // ---- even chunk t: compute bufA, prefetch t+1 -> bufB ----
        if (t + 1 < CHUNKS)
            stage_chunk(xblk + (long)(t + 1) * CHUNK_ROWS * KDIM, bufB, tid);
        compute_chunk(bufA, wf, l16, q, acc);
        __syncthreads();   // drains loads(t+1) after a full compute phase
        {
            const long row0 = row_base + (long)t * CHUNK_ROWS;
#pragma unroll
            for (int nt = 0; nt < 2; ++nt)
#pragma unroll
                for (int r = 0; r < 4; ++r)
                    out[(row0 + q * 4 + r) * NDIM + n0 + nt * 16 + l16] = acc[nt][r] + bv[nt];
        }

        // ---- odd chunk t+1: compute bufB, prefetch t+2 -> bufA ----
        if (t + 2 < CHUNKS)
            stage_chunk(xblk + (long)(t + 2) * CHUNK_ROWS * KDIM, bufA, tid);
        compute_chunk(bufB, wf, l16, q, acc);
        __syncthreads();
        {
            const long row0 = row_base + (long)(t + 1) * CHUNK_ROWS;
#pragma unroll
            for (int nt = 0; nt < 2; ++nt)
#pragma unroll
                for (int r = 0; r < 4; ++r)
                    out[(row0 + q * 4 + r) * NDIM + n0 + nt * 16 + l16] = acc[nt][r] + bv[nt];
        }
    }
}

extern "C" void kernel_launch(void* const* d_in, const int* in_sizes, int n_in,
                              void* d_out, int out_size, void* d_ws, size_t ws_size,
                              hipStream_t stream) {
    const float* x    = (const float*)d_in[0];
    const float* w    = (const float*)d_in[1];
    const float* bias = (const float*)d_in[2];
    float* out = (float*)d_out;
    bf16* wb   = (bf16*)d_ws;   // 256*512*2 = 256 KB scratch

    wcvt_kernel<<<(NDIM * KDIM) / (256 * 4), 256, 0, stream>>>(w, wb);
    gemm_kernel<<<BATCH_ / ROWS_PER_BLOCK, 512, 0, stream>>>(x, wb, bias, out);
}